// Round 1
// baseline (165.920 us; speedup 1.0000x reference)
//
#include <hip/hip_runtime.h>
#include <hip/hip_bf16.h>

typedef unsigned short u16;
typedef unsigned int u32;

#define NEG_SLOPE 0.2f
#define ZTOLF 1e-9f
#define CAP 256          // max tracked nonzeros per column/row of S (mean ~102, sigma ~10)

__device__ __forceinline__ float b2f(u16 v) {
  return __uint_as_float(((u32)v) << 16);
}
__device__ __forceinline__ u16 f2b(float f) {
  u32 u = __float_as_uint(f);
  return (u16)((u + 0x7fffu + ((u >> 16) & 1u)) >> 16);  // RNE
}
// dtype-flex input load: isbf=1 -> bf16 buffer, isbf=0 -> fp32 buffer
__device__ __forceinline__ float ldin(const void* p, size_t i, int isbf) {
  return isbf ? b2f(((const u16*)p)[i]) : ((const float*)p)[i];
}

// ---------------- K0: detect input dtype + zero the (padded) counters ----------------
__global__ __launch_bounds__(256) void k_detect(const u32* __restrict__ xw,
                                                u32* __restrict__ flag,
                                                uint4* __restrict__ cnt_p4,   // 2048*16 u32 = 8192 uint4
                                                uint4* __restrict__ rcnt4) {  // 2048 u32 = 512 uint4
  __shared__ u32 cnt_s[4];
  const int tid = threadIdx.x;
  const uint4 z = make_uint4(0u, 0u, 0u, 0u);
  for (int i = tid; i < 8192; i += 256) cnt_p4[i] = z;
  for (int i = tid; i < 512; i += 256) rcnt4[i] = z;
  const u32 w = xw[tid];
  const u32 e = (w >> 7) & 0xffu;
  const int in = (e >= 118u && e <= 131u) ? 1 : 0;
  unsigned long long bal = __ballot(in);
  const int lane = tid & 63, wid = tid >> 6;
  if (lane == 0) cnt_s[wid] = (u32)__popcll(bal);
  __syncthreads();
  if (tid == 0) {
    u32 tot = cnt_s[0] + cnt_s[1] + cnt_s[2] + cnt_s[3];
    flag[0] = (tot >= 128u) ? 1u : 0u;
  }
}

// ---------------- K1: Wx[bp][n][f] (bf16) + fused s1t/s2t epilogue ----------------
__global__ __launch_bounds__(256) void k_wx(const void* __restrict__ x,
                                            const void* __restrict__ W,
                                            const void* __restrict__ a,
                                            u16* __restrict__ Wx,
                                            float* __restrict__ s1t,
                                            float* __restrict__ s2t,
                                            const u32* __restrict__ flag) {
  __shared__ float Wt[64 * 68];  // [g][f]; aliased as red1/red2 in epilogue
  __shared__ float Xs[64 * 64];  // [g][n]
  const int isbf = (int)flag[0];
  const int tid = threadIdx.x;
  const int n0 = blockIdx.x * 64;
  const int bp = blockIdx.y;
  const int b = bp >> 2, p = bp & 3;
  const int tn = tid & 15, tf = tid >> 4;
  float acc[4][4] = {{0.f}};
  const size_t Wbase = (size_t)p * 64 * 128;
  const size_t xbase = (size_t)b * 128 * 2048;
  for (int kt = 0; kt < 2; ++kt) {
    const int g0 = kt * 64;
#pragma unroll
    for (int j = 0; j < 16; ++j) {
      int idx = tid + j * 256;
      int f = idx >> 6, g = idx & 63;
      Wt[g * 68 + f] = ldin(W, Wbase + (size_t)f * 128 + g0 + g, isbf);
    }
#pragma unroll
    for (int j = 0; j < 16; ++j) {
      int idx = tid + j * 256;
      int g = idx >> 6, nn = idx & 63;
      Xs[g * 64 + nn] = ldin(x, xbase + (size_t)(g0 + g) * 2048 + n0 + nn, isbf);
    }
    __syncthreads();
#pragma unroll 4
    for (int g = 0; g < 64; ++g) {
      float4 wv = *(const float4*)&Wt[g * 68 + tf * 4];
      float4 xv = *(const float4*)&Xs[g * 64 + tn * 4];
      acc[0][0] += wv.x * xv.x; acc[0][1] += wv.x * xv.y; acc[0][2] += wv.x * xv.z; acc[0][3] += wv.x * xv.w;
      acc[1][0] += wv.y * xv.x; acc[1][1] += wv.y * xv.y; acc[1][2] += wv.y * xv.z; acc[1][3] += wv.y * xv.w;
      acc[2][0] += wv.z * xv.x; acc[2][1] += wv.z * xv.y; acc[2][2] += wv.z * xv.z; acc[2][3] += wv.z * xv.w;
      acc[3][0] += wv.w * xv.x; acc[3][1] += wv.w * xv.y; acc[3][2] += wv.w * xv.z; acc[3][3] += wv.w * xv.w;
    }
    __syncthreads();  // also makes Wt/Xs safe to reuse after the loop
  }
#pragma unroll
  for (int j = 0; j < 4; ++j) {
    int n = n0 + tn * 4 + j;
    u32 lo = (u32)f2b(acc[0][j]) | ((u32)f2b(acc[1][j]) << 16);
    u32 hi = (u32)f2b(acc[2][j]) | ((u32)f2b(acc[3][j]) << 16);
    *(uint2*)(Wx + ((size_t)(bp * 2048 + n) * 64 + tf * 4)) = make_uint2(lo, hi);
  }
  // fused s1/s2 epilogue: LDS reduce across tf. red layout [n_local][17] breaks conflicts.
  float a1v[4], a2v[4];
#pragma unroll
  for (int fi = 0; fi < 4; ++fi) {
    a1v[fi] = ldin(a, (size_t)p * 128 + tf * 4 + fi, isbf);
    a2v[fi] = ldin(a, (size_t)p * 128 + 64 + tf * 4 + fi, isbf);
  }
  float* red1 = Wt;             // 64*17 floats
  float* red2 = Wt + 64 * 17;   // 64*17 floats
#pragma unroll
  for (int j = 0; j < 4; ++j) {
    float p1 = a1v[0] * acc[0][j] + a1v[1] * acc[1][j] + a1v[2] * acc[2][j] + a1v[3] * acc[3][j];
    float p2 = a2v[0] * acc[0][j] + a2v[1] * acc[1][j] + a2v[2] * acc[2][j] + a2v[3] * acc[3][j];
    red1[(tn * 4 + j) * 17 + tf] = p1;
    red2[(tn * 4 + j) * 17 + tf] = p2;
  }
  __syncthreads();
  if (tid < 64) {
    float v1 = 0.f, v2 = 0.f;
#pragma unroll
    for (int k = 0; k < 16; ++k) {
      v1 += red1[tid * 17 + k];
      v2 += red2[tid * 17 + k];
    }
    s1t[(size_t)(n0 + tid) * 16 + bp] = v1;
    s2t[(size_t)(n0 + tid) * 16 + bp] = v2;
  }
}

// ---------------- K2: block per row. Row lists via prefix-scan (no atomics);
// column lists via line-padded atomics (cnt_p stride 16 u32 = 1/cacheline). ----------------
__global__ __launch_bounds__(256) void k_csc(const void* __restrict__ S,
                                             u32* __restrict__ cnt_p,
                                             u32* __restrict__ col_m,
                                             float* __restrict__ col_v,
                                             u32* __restrict__ rcnt,
                                             u32* __restrict__ row_n,
                                             const u32* __restrict__ flag) {
  __shared__ u32 wsum[4];
  const int isbf = (int)flag[0];
  const int m = blockIdx.x;
  const int tid = threadIdx.x;
  const int lane = tid & 63, wid = tid >> 6;
  const int n0 = tid * 8;
  float v[8];
  if (isbf) {
    uint4 pk = ((const uint4*)S)[(size_t)m * 256 + tid];
    u32 wv[4] = {pk.x, pk.y, pk.z, pk.w};
#pragma unroll
    for (int j = 0; j < 4; ++j) {
      v[2 * j]     = b2f((u16)(wv[j] & 0xffffu));
      v[2 * j + 1] = b2f((u16)(wv[j] >> 16));
    }
  } else {
    float4 f0 = ((const float4*)S)[(size_t)m * 512 + 2 * tid];
    float4 f1 = ((const float4*)S)[(size_t)m * 512 + 2 * tid + 1];
    v[0] = f0.x; v[1] = f0.y; v[2] = f0.z; v[3] = f0.w;
    v[4] = f1.x; v[5] = f1.y; v[6] = f1.z; v[7] = f1.w;
  }
  // row-mask flags (|S+I| > tol)
  u32 rflags = 0, rc = 0;
#pragma unroll
  for (int j = 0; j < 8; ++j) {
    const int n = n0 + j;
    const float svd = (n == m) ? v[j] + 1.f : v[j];
    if (fabsf(svd) > ZTOLF) { rflags |= 1u << j; rc++; }
  }
  // block exclusive scan: wave shuffle scan + cross-wave via LDS
  u32 inc = rc;
#pragma unroll
  for (int off = 1; off < 64; off <<= 1) {
    u32 y = __shfl_up(inc, off);
    if (lane >= off) inc += y;
  }
  if (lane == 63) wsum[wid] = inc;
  __syncthreads();
  u32 wbase = 0;
#pragma unroll
  for (int k = 0; k < 4; ++k) wbase += (k < wid) ? wsum[k] : 0u;
  u32 pos = wbase + inc - rc;
#pragma unroll
  for (int j = 0; j < 8; ++j) {
    if ((rflags >> j) & 1u) {
      if (pos < CAP) row_n[(size_t)m * CAP + pos] = (u32)(n0 + j);
      pos++;
    }
  }
  if (tid == 255) rcnt[m] = min(wbase + inc, (u32)CAP);
  // column entries: padded-line atomics (2048 distinct lines, ~102 ops each)
#pragma unroll
  for (int j = 0; j < 8; ++j) {
    const float sv = v[j];
    if (sv != 0.f) {
      const int n = n0 + j;
      u32 slot = atomicAdd(&cnt_p[(size_t)n * 16], 1u);
      if (slot < CAP) {
        col_m[(size_t)n * CAP + slot] = (u32)m;
        col_v[(size_t)n * CAP + slot] = sv;
      }
    }
  }
}

// ---------------- K3: sparse per-row softmax stats -> stat3[m][bp] = (s2, rowmax, invsum, 0) ----------------
__global__ __launch_bounds__(256) void k_rows(const u32* __restrict__ rcnt,
                                              const u32* __restrict__ row_n,
                                              const float* __restrict__ s1t,
                                              const float* __restrict__ s2t,
                                              float4* __restrict__ stat3) {
  const int tid = threadIdx.x;
  const int lane = tid & 63, wv = tid >> 6;
  const int m = blockIdx.x * 4 + wv;      // one wave per row
  const int c2 = min((int)rcnt[m], CAP);
  int ne[4];
#pragma unroll
  for (int I = 0; I < 4; ++I) {
    int i = lane + I * 64;
    ne[I] = (i < c2) ? (int)row_n[(size_t)m * CAP + i] : -1;
  }
  const float s2v = (lane < 16) ? s2t[(size_t)m * 16 + lane] : 0.f;
  float my_rmx = 0.f, my_inv = 0.f;
#pragma unroll
  for (int g = 0; g < 4; ++g) {           // bp groups of 4
    float4 sg[4];
#pragma unroll
    for (int I = 0; I < 4; ++I)
      sg[I] = (ne[I] >= 0) ? *(const float4*)&s1t[(size_t)ne[I] * 16 + g * 4]
                           : make_float4(-3e38f, -3e38f, -3e38f, -3e38f);
#pragma unroll
    for (int q = 0; q < 4; ++q) {
      const int bp = g * 4 + q;
      const float s2m = __shfl(s2v, bp);
      float s1max = -3e38f;
#pragma unroll
      for (int I = 0; I < 4; ++I) {
        float xv = (q == 0) ? sg[I].x : (q == 1) ? sg[I].y : (q == 2) ? sg[I].z : sg[I].w;
        s1max = fmaxf(s1max, xv);
      }
#pragma unroll
      for (int off = 32; off; off >>= 1) s1max = fmaxf(s1max, __shfl_xor(s1max, off));
      float rmx = s2m + s1max;
      rmx = rmx >= 0.f ? rmx : NEG_SLOPE * rmx;
      float sm = 0.f;
#pragma unroll
      for (int I = 0; I < 4; ++I) {
        float xv = (q == 0) ? sg[I].x : (q == 1) ? sg[I].y : (q == 2) ? sg[I].z : sg[I].w;
        float e = xv + s2m;
        e = e >= 0.f ? e : NEG_SLOPE * e;
        sm += __expf(e - rmx);            // invalid entries: e ~ -3e38 -> exp -> 0
      }
#pragma unroll
      for (int off = 32; off; off >>= 1) sm += __shfl_xor(sm, off);
      const bool any = (s1max > -1e38f);
      const float rmxo = any ? rmx : 0.f;
      const float inv = any ? 1.f / sm : 0.f;
      if (lane == bp) { my_rmx = rmxo; my_inv = inv; }
    }
  }
  if (lane < 16)
    stat3[(size_t)m * 16 + lane] = make_float4(s2v, my_rmx, my_inv, 0.f);
}

// ---------------- K4: y[bp][f][n] = relu( sum_m Wx[bp][m][f] * S[m][n] * aij[bp][m][n] ) ----------------
// 1024 threads: 16 waves = 4 bp-groups x 4 entry-quarters. lane -> (bp_local, f4), uint2 Wx loads.
__global__ __launch_bounds__(1024, 8) void k_out(const u16* __restrict__ Wx,
                                                 const u32* __restrict__ cnt_p,
                                                 const u32* __restrict__ col_m,
                                                 const float* __restrict__ col_v,
                                                 const float* __restrict__ s1t,
                                                 const float4* __restrict__ stat3,
                                                 void* __restrict__ out,
                                                 const u32* __restrict__ flag) {
  __shared__ u32 lds_m[CAP];
  __shared__ float lds_w[CAP * 16];   // [i][bp], 16 KB
  __shared__ float lds_r[3 * 256 * 4]; // quarter partials (12 KB); [0..255] doubles as sv temp
  __shared__ float s1s[16];
  const int isbf = (int)flag[0];
  const int tid = threadIdx.x;
  const int bid = blockIdx.x;
  const int n = ((bid & 7) << 8) | (bid >> 3);   // XCD swizzle
  const int c = min((int)cnt_p[(size_t)n * 16], CAP);
  const int cpad = (c + 15) & ~15;               // 4 quarters x unroll-4
  if (tid < 16) s1s[tid] = s1t[(size_t)n * 16 + tid];
  if (tid < cpad) {
    lds_m[tid] = (tid < c) ? col_m[(size_t)n * CAP + tid] : 0u;
    lds_r[tid] = (tid < c) ? col_v[(size_t)n * CAP + tid] : 0.f;
  }
  __syncthreads();
  // stage 2: weights, one (entry,bp) pair per work item
  const int totk = cpad * 16;
  for (int k = tid; k < totk; k += 1024) {
    const int i = k >> 4, bp = k & 15;
    float w = 0.f;
    if (i < c) {
      const int m = (int)lds_m[i];
      const float sv = lds_r[i];
      const float svd = (m == n) ? sv + 1.f : sv;
      if (fabsf(svd) > ZTOLF) {
        float4 s = stat3[(size_t)m * 16 + bp];   // (s2, rowmax, invsum)
        float e = s1s[bp] + s.x;
        e = e >= 0.f ? e : NEG_SLOPE * e;
        w = sv * __expf(e - s.y) * s.z;
      }
    }
    lds_w[k] = w;
  }
  __syncthreads();
  // stage 3: gather. wave wvi: bp-group wvi&3, quarter h = wvi>>2; lane: bp_local = lane>>4, f4 = lane&15
  const int lane = tid & 63, wvi = tid >> 6;
  const int h = wvi >> 2;
  const int bp = (wvi & 3) * 4 + (lane >> 4);
  const int f4 = lane & 15;
  const u16* wxp = Wx + (size_t)bp * (2048 * 64) + f4 * 4;
  float ac0 = 0.f, ac1 = 0.f, ac2 = 0.f, ac3 = 0.f;
  for (int base = h * 4; base < cpad; base += 16) {
    uint2 wd[4]; float ww[4];
#pragma unroll
    for (int j = 0; j < 4; ++j) {
      const int i = base + j;
      const int m = (int)lds_m[i];
      wd[j] = *(const uint2*)(wxp + (size_t)m * 64);
      ww[j] = lds_w[i * 16 + bp];
    }
#pragma unroll
    for (int j = 0; j < 4; ++j) {
      const float w = ww[j];
      ac0 += w * b2f((u16)(wd[j].x & 0xffffu));
      ac1 += w * b2f((u16)(wd[j].x >> 16));
      ac2 += w * b2f((u16)(wd[j].y & 0xffffu));
      ac3 += w * b2f((u16)(wd[j].y >> 16));
    }
  }
  if (h > 0)
    *(float4*)&lds_r[((h - 1) * 256 + bp * 16 + f4) * 4] = make_float4(ac0, ac1, ac2, ac3);
  __syncthreads();
  if (h == 0) {
#pragma unroll
    for (int q = 0; q < 3; ++q) {
      float4 r = *(const float4*)&lds_r[(q * 256 + bp * 16 + f4) * 4];
      ac0 += r.x; ac1 += r.y; ac2 += r.z; ac3 += r.w;
    }
    const float o0 = fmaxf(ac0, 0.f), o1 = fmaxf(ac1, 0.f);
    const float o2 = fmaxf(ac2, 0.f), o3 = fmaxf(ac3, 0.f);
    const size_t r0 = (size_t)(bp * 64 + f4 * 4);
    if (isbf) {
      u16* ob = (u16*)out;
      ob[(r0 + 0) * 2048 + n] = f2b(o0);
      ob[(r0 + 1) * 2048 + n] = f2b(o1);
      ob[(r0 + 2) * 2048 + n] = f2b(o2);
      ob[(r0 + 3) * 2048 + n] = f2b(o3);
    } else {
      float* of = (float*)out;
      of[(r0 + 0) * 2048 + n] = o0;
      of[(r0 + 1) * 2048 + n] = o1;
      of[(r0 + 2) * 2048 + n] = o2;
      of[(r0 + 3) * 2048 + n] = o3;
    }
  }
}

extern "C" void kernel_launch(void* const* d_in, const int* in_sizes, int n_in,
                              void* d_out, int out_size, void* d_ws, size_t ws_size,
                              hipStream_t stream) {
  // inputs (dtype auto-detected): x (4,128,2048), a (4,1,128), W (4,1,64,128), S (1,2048,2048)
  const void* x = d_in[0];
  const void* a = d_in[1];
  const void* W = d_in[2];
  const void* S = d_in[3];

  char* ws = (char*)d_ws;
  u16* Wx      = (u16*)ws;                               // 16*2048*64*2 = 4 MiB
  float* s1t   = (float*)(ws + 4u * 1024 * 1024);        // 128 KiB
  float* s2t   = s1t + 2048 * 16;                        // 128 KiB
  float4* stat3= (float4*)(s2t + 2048 * 16);             // 512 KiB
  u32* cnt_p   = (u32*)((char*)stat3 + 512u * 1024);     // 2048*16*4 = 128 KiB (1 counter / 64B line)
  u32* rcnt    = cnt_p + 2048 * 16;                      // 8 KiB
  u32* col_m   = rcnt + 2048;                            // 2 MiB
  float* col_v = (float*)(col_m + 2048 * CAP);           // 2 MiB
  u32* row_n   = (u32*)(col_v + 2048 * CAP);             // 2 MiB
  u32* flag    = row_n + 2048 * CAP;                     // 4 B
  // total ~10.9 MiB

  k_detect<<<1, 256, 0, stream>>>((const u32*)x, flag, (uint4*)cnt_p, (uint4*)rcnt);
  k_wx<<<dim3(32, 16), 256, 0, stream>>>(x, W, a, Wx, s1t, s2t, flag);
  k_csc<<<2048, 256, 0, stream>>>(S, cnt_p, col_m, col_v, rcnt, row_n, flag);
  k_rows<<<512, 256, 0, stream>>>(rcnt, row_n, s1t, s2t, stat3);
  k_out<<<2048, 1024, 0, stream>>>(Wx, cnt_p, col_m, col_v, s1t, stat3, d_out, flag);
}

// Round 2
// 155.493 us; speedup vs baseline: 1.0671x; 1.0671x over previous
//
#include <hip/hip_runtime.h>
#include <hip/hip_bf16.h>

typedef unsigned short u16;
typedef unsigned int u32;

#define NEG_SLOPE 0.2f
#define ZTOLF 1e-9f
#define CAP 256          // max tracked nonzeros per column/row of S (mean ~102, sigma ~10)

__device__ __forceinline__ float b2f(u16 v) {
  return __uint_as_float(((u32)v) << 16);
}
__device__ __forceinline__ u16 f2b(float f) {
  u32 u = __float_as_uint(f);
  return (u16)((u + 0x7fffu + ((u >> 16) & 1u)) >> 16);  // RNE
}
// dtype-flex input load: isbf=1 -> bf16 buffer, isbf=0 -> fp32 buffer
__device__ __forceinline__ float ldin(const void* p, size_t i, int isbf) {
  return isbf ? b2f(((const u16*)p)[i]) : ((const float*)p)[i];
}

// ---------------- K0: detect input dtype + zero the (padded) counters ----------------
__global__ __launch_bounds__(256) void k_detect(const u32* __restrict__ xw,
                                                u32* __restrict__ flag,
                                                uint4* __restrict__ cnt_p4) {  // 2048*16 u32 = 8192 uint4
  __shared__ u32 cnt_s[4];
  const int tid = threadIdx.x;
  const uint4 z = make_uint4(0u, 0u, 0u, 0u);
  for (int i = tid; i < 8192; i += 256) cnt_p4[i] = z;
  const u32 w = xw[tid];
  const u32 e = (w >> 7) & 0xffu;
  const int in = (e >= 118u && e <= 131u) ? 1 : 0;
  unsigned long long bal = __ballot(in);
  const int lane = tid & 63, wid = tid >> 6;
  if (lane == 0) cnt_s[wid] = (u32)__popcll(bal);
  __syncthreads();
  if (tid == 0) {
    u32 tot = cnt_s[0] + cnt_s[1] + cnt_s[2] + cnt_s[3];
    flag[0] = (tot >= 128u) ? 1u : 0u;
  }
}

// ---------------- K1: Wx[bp][n][f] (bf16) + fused s1t/s2t epilogue ----------------
__global__ __launch_bounds__(256) void k_wx(const void* __restrict__ x,
                                            const void* __restrict__ W,
                                            const void* __restrict__ a,
                                            u16* __restrict__ Wx,
                                            float* __restrict__ s1t,
                                            float* __restrict__ s2t,
                                            const u32* __restrict__ flag) {
  __shared__ float Wt[64 * 68];  // [g][f]; aliased as red1/red2 in epilogue
  __shared__ float Xs[64 * 64];  // [g][n]
  const int isbf = (int)flag[0];
  const int tid = threadIdx.x;
  const int n0 = blockIdx.x * 64;
  const int bp = blockIdx.y;
  const int b = bp >> 2, p = bp & 3;
  const int tn = tid & 15, tf = tid >> 4;
  float acc[4][4] = {{0.f}};
  const size_t Wbase = (size_t)p * 64 * 128;
  const size_t xbase = (size_t)b * 128 * 2048;
  for (int kt = 0; kt < 2; ++kt) {
    const int g0 = kt * 64;
#pragma unroll
    for (int j = 0; j < 16; ++j) {
      int idx = tid + j * 256;
      int f = idx >> 6, g = idx & 63;
      Wt[g * 68 + f] = ldin(W, Wbase + (size_t)f * 128 + g0 + g, isbf);
    }
#pragma unroll
    for (int j = 0; j < 16; ++j) {
      int idx = tid + j * 256;
      int g = idx >> 6, nn = idx & 63;
      Xs[g * 64 + nn] = ldin(x, xbase + (size_t)(g0 + g) * 2048 + n0 + nn, isbf);
    }
    __syncthreads();
#pragma unroll 4
    for (int g = 0; g < 64; ++g) {
      float4 wv = *(const float4*)&Wt[g * 68 + tf * 4];
      float4 xv = *(const float4*)&Xs[g * 64 + tn * 4];
      acc[0][0] += wv.x * xv.x; acc[0][1] += wv.x * xv.y; acc[0][2] += wv.x * xv.z; acc[0][3] += wv.x * xv.w;
      acc[1][0] += wv.y * xv.x; acc[1][1] += wv.y * xv.y; acc[1][2] += wv.y * xv.z; acc[1][3] += wv.y * xv.w;
      acc[2][0] += wv.z * xv.x; acc[2][1] += wv.z * xv.y; acc[2][2] += wv.z * xv.z; acc[2][3] += wv.z * xv.w;
      acc[3][0] += wv.w * xv.x; acc[3][1] += wv.w * xv.y; acc[3][2] += wv.w * xv.z; acc[3][3] += wv.w * xv.w;
    }
    __syncthreads();  // also makes Wt/Xs safe to reuse after the loop
  }
#pragma unroll
  for (int j = 0; j < 4; ++j) {
    int n = n0 + tn * 4 + j;
    u32 lo = (u32)f2b(acc[0][j]) | ((u32)f2b(acc[1][j]) << 16);
    u32 hi = (u32)f2b(acc[2][j]) | ((u32)f2b(acc[3][j]) << 16);
    *(uint2*)(Wx + ((size_t)(bp * 2048 + n) * 64 + tf * 4)) = make_uint2(lo, hi);
  }
  // fused s1/s2 epilogue: LDS reduce across tf. red layout [n_local][17] breaks conflicts.
  float a1v[4], a2v[4];
#pragma unroll
  for (int fi = 0; fi < 4; ++fi) {
    a1v[fi] = ldin(a, (size_t)p * 128 + tf * 4 + fi, isbf);
    a2v[fi] = ldin(a, (size_t)p * 128 + 64 + tf * 4 + fi, isbf);
  }
  float* red1 = Wt;             // 64*17 floats
  float* red2 = Wt + 64 * 17;   // 64*17 floats
#pragma unroll
  for (int j = 0; j < 4; ++j) {
    float p1 = a1v[0] * acc[0][j] + a1v[1] * acc[1][j] + a1v[2] * acc[2][j] + a1v[3] * acc[3][j];
    float p2 = a2v[0] * acc[0][j] + a2v[1] * acc[1][j] + a2v[2] * acc[2][j] + a2v[3] * acc[3][j];
    red1[(tn * 4 + j) * 17 + tf] = p1;
    red2[(tn * 4 + j) * 17 + tf] = p2;
  }
  __syncthreads();
  if (tid < 64) {
    float v1 = 0.f, v2 = 0.f;
#pragma unroll
    for (int k = 0; k < 16; ++k) {
      v1 += red1[tid * 17 + k];
      v2 += red2[tid * 17 + k];
    }
    s1t[(size_t)(n0 + tid) * 16 + bp] = v1;
    s2t[(size_t)(n0 + tid) * 16 + bp] = v2;
  }
}

// ---------------- K2: block per row. Builds column lists (atomics) AND computes the
// per-row softmax stats inline (row list kept in LDS via prefix-scan; k_rows fused away).
// stat3[m][bp] = (s2, rowmax, invsum, 0) ----------------
__global__ __launch_bounds__(256) void k_csc(const void* __restrict__ S,
                                             u32* __restrict__ cnt_p,
                                             u32* __restrict__ col_m,
                                             float* __restrict__ col_v,
                                             const float* __restrict__ s1t,
                                             const float* __restrict__ s2t,
                                             float4* __restrict__ stat3,
                                             const u32* __restrict__ flag) {
  __shared__ u32 wsum[4];
  __shared__ u32 ls_n[CAP];      // compacted nonzero-row column indices of row m
  __shared__ u32 c2s;
  __shared__ float red[256];     // cross-thread reductions
  __shared__ float Mred[16];
  const int isbf = (int)flag[0];
  const int m = blockIdx.x;
  const int tid = threadIdx.x;
  const int lane = tid & 63, wid = tid >> 6;
  const int n0 = tid * 8;
  float v[8];
  if (isbf) {
    uint4 pk = ((const uint4*)S)[(size_t)m * 256 + tid];
    u32 wv[4] = {pk.x, pk.y, pk.z, pk.w};
#pragma unroll
    for (int j = 0; j < 4; ++j) {
      v[2 * j]     = b2f((u16)(wv[j] & 0xffffu));
      v[2 * j + 1] = b2f((u16)(wv[j] >> 16));
    }
  } else {
    float4 f0 = ((const float4*)S)[(size_t)m * 512 + 2 * tid];
    float4 f1 = ((const float4*)S)[(size_t)m * 512 + 2 * tid + 1];
    v[0] = f0.x; v[1] = f0.y; v[2] = f0.z; v[3] = f0.w;
    v[4] = f1.x; v[5] = f1.y; v[6] = f1.z; v[7] = f1.w;
  }
  // row-mask flags (|S+I| > tol)
  u32 rflags = 0, rc = 0;
#pragma unroll
  for (int j = 0; j < 8; ++j) {
    const int n = n0 + j;
    const float svd = (n == m) ? v[j] + 1.f : v[j];
    if (fabsf(svd) > ZTOLF) { rflags |= 1u << j; rc++; }
  }
  // block exclusive scan: wave shuffle scan + cross-wave via LDS
  u32 inc = rc;
#pragma unroll
  for (int off = 1; off < 64; off <<= 1) {
    u32 y = __shfl_up(inc, off);
    if (lane >= off) inc += y;
  }
  if (lane == 63) wsum[wid] = inc;
  __syncthreads();
  u32 wbase = 0;
#pragma unroll
  for (int k = 0; k < 4; ++k) wbase += (k < wid) ? wsum[k] : 0u;
  u32 pos = wbase + inc - rc;
#pragma unroll
  for (int j = 0; j < 8; ++j) {
    if ((rflags >> j) & 1u) {
      if (pos < CAP) ls_n[pos] = (u32)(n0 + j);
      pos++;
    }
  }
  if (tid == 255) c2s = min(wbase + inc, (u32)CAP);
  // column entries: padded-line atomics (2048 distinct lines, ~102 ops each)
#pragma unroll
  for (int j = 0; j < 8; ++j) {
    const float sv = v[j];
    if (sv != 0.f) {
      const int n = n0 + j;
      u32 slot = atomicAdd(&cnt_p[(size_t)n * 16], 1u);
      if (slot < CAP) {
        col_m[(size_t)n * CAP + slot] = (u32)m;
        col_v[(size_t)n * CAP + slot] = sv;
      }
    }
  }
  __syncthreads();
  // ---- fused per-row softmax stats (was k_rows) ----
  // thread -> (bp = tid&15, sub = tid>>4); each (bp,sub) strides entries by 16.
  const int c2 = (int)c2s;
  const int bp = tid & 15, sub = tid >> 4;
  const float s2v = s2t[(size_t)m * 16 + bp];
  float ev[16];
  float mymax = -3e38f;
#pragma unroll
  for (int k = 0; k < 16; ++k) {
    const int i = sub + k * 16;
    float e = -3e38f;
    if (i < c2) {
      const int nn = (int)ls_n[i];
      float s1 = s1t[(size_t)nn * 16 + bp];
      e = s1 + s2v;
      e = e >= 0.f ? e : NEG_SLOPE * e;   // leaky is monotone -> max commutes
    }
    ev[k] = e;
    mymax = fmaxf(mymax, e);
  }
  red[tid] = mymax;
  __syncthreads();
  if (tid < 16) {
    float M = -3e38f;
#pragma unroll
    for (int s = 0; s < 16; ++s) M = fmaxf(M, red[s * 16 + tid]);
    Mred[tid] = M;
  }
  __syncthreads();
  const float M = Mred[bp];
  float ssum = 0.f;
#pragma unroll
  for (int k = 0; k < 16; ++k) ssum += __expf(ev[k] - M);  // invalid -> exp(-inf) = 0
  __syncthreads();       // red[] reuse
  red[tid] = ssum;
  __syncthreads();
  if (tid < 16) {
    float Sm = 0.f;
#pragma unroll
    for (int s = 0; s < 16; ++s) Sm += red[s * 16 + tid];
    const float Mv = Mred[tid];
    const bool any = (Mv > -1e38f);
    const float rmx = any ? Mv : 0.f;
    const float inv = any ? 1.f / Sm : 0.f;
    const float s2o = s2t[(size_t)m * 16 + tid];
    stat3[(size_t)m * 16 + tid] = make_float4(s2o, rmx, inv, 0.f);
  }
}

// ---------------- K4: y[bp][f][n] = relu( sum_m Wx[bp][m][f] * S[m][n] * aij[bp][m][n] ) ----------------
// v2: 256-thread blocks, bp split across blocks. grid = 2048 n x 4 bp-groups.
// XCD-pinned: xcd = bid&7 -> bpg = xcd>>1, so each XCD's Wx working set is 1 MiB (L2-resident).
__global__ __launch_bounds__(256, 8) void k_out(const u16* __restrict__ Wx,
                                                const u32* __restrict__ cnt_p,
                                                const u32* __restrict__ col_m,
                                                const float* __restrict__ col_v,
                                                const float* __restrict__ s1t,
                                                const float4* __restrict__ stat3,
                                                void* __restrict__ out,
                                                const u32* __restrict__ flag) {
  __shared__ u32 lds_m[CAP];
  __shared__ float lds_v[CAP];
  __shared__ float lds_w[CAP * 4];   // [i][bp4], 4 KB
  __shared__ float lds_r[3 * 256];   // quarter partials (3 KB)
  __shared__ float s1s4[4];
  const int isbf = (int)flag[0];
  const int tid = threadIdx.x;
  const int bid = blockIdx.x;
  const int xcd = bid & 7, lin = bid >> 3;
  const int bpg = xcd >> 1;                    // 4 bp per block; 2 XCDs per bpg
  const int n = ((xcd & 1) << 10) | lin;       // 2048 columns
  const int c = min((int)cnt_p[(size_t)n * 16], CAP);
  const int cpad = (c + 15) & ~15;             // 4 quarters x unroll-4
  if (tid < 4) s1s4[tid] = s1t[(size_t)n * 16 + bpg * 4 + tid];
  if (tid < cpad) {
    lds_m[tid] = (tid < c) ? col_m[(size_t)n * CAP + tid] : 0u;
    lds_v[tid] = (tid < c) ? col_v[(size_t)n * CAP + tid] : 0.f;
  }
  __syncthreads();
  // stage 2: weights for this block's 4 bp
  const int totk = cpad * 4;
  for (int k = tid; k < totk; k += 256) {
    const int i = k >> 2, bp4 = k & 3;
    const int bp = bpg * 4 + bp4;
    float w = 0.f;
    if (i < c) {
      const int mm = (int)lds_m[i];
      const float sv = lds_v[i];
      const float svd = (mm == n) ? sv + 1.f : sv;
      if (fabsf(svd) > ZTOLF) {
        float4 s = stat3[(size_t)mm * 16 + bp];   // (s2, rowmax, invsum)
        float e = s1s4[bp4] + s.x;
        e = e >= 0.f ? e : NEG_SLOPE * e;
        w = sv * __expf(e - s.y) * s.z;
      }
    }
    lds_w[k] = w;   // k = i*4 + bp4
  }
  __syncthreads();
  // stage 3: gather. wave h = entry-quarter; lane: bp4 = lane>>4, f4 = lane&15
  const int lane = tid & 63, h = tid >> 6;
  const int bp4 = lane >> 4, bp = bpg * 4 + bp4;
  const int f4 = lane & 15;
  const u16* wxp = Wx + (size_t)bp * (2048 * 64) + f4 * 4;
  float ac0 = 0.f, ac1 = 0.f, ac2 = 0.f, ac3 = 0.f;
  for (int base = h * 4; base < cpad; base += 16) {
    uint2 wd[4]; float ww[4];
#pragma unroll
    for (int j = 0; j < 4; ++j) {
      const int i = base + j;
      const int mm = (int)lds_m[i];
      wd[j] = *(const uint2*)(wxp + (size_t)mm * 64);
      ww[j] = lds_w[i * 4 + bp4];
    }
#pragma unroll
    for (int j = 0; j < 4; ++j) {
      const float w = ww[j];
      ac0 += w * b2f((u16)(wd[j].x & 0xffffu));
      ac1 += w * b2f((u16)(wd[j].x >> 16));
      ac2 += w * b2f((u16)(wd[j].y & 0xffffu));
      ac3 += w * b2f((u16)(wd[j].y >> 16));
    }
  }
  if (h > 0)
    *(float4*)&lds_r[(h - 1) * 256 + (bp4 * 16 + f4) * 4] = make_float4(ac0, ac1, ac2, ac3);
  __syncthreads();
  if (h == 0) {
#pragma unroll
    for (int q = 0; q < 3; ++q) {
      float4 r = *(const float4*)&lds_r[q * 256 + (bp4 * 16 + f4) * 4];
      ac0 += r.x; ac1 += r.y; ac2 += r.z; ac3 += r.w;
    }
    const float o0 = fmaxf(ac0, 0.f), o1 = fmaxf(ac1, 0.f);
    const float o2 = fmaxf(ac2, 0.f), o3 = fmaxf(ac3, 0.f);
    const size_t r0 = (size_t)(bp * 64 + f4 * 4);
    if (isbf) {
      u16* ob = (u16*)out;
      ob[(r0 + 0) * 2048 + n] = f2b(o0);
      ob[(r0 + 1) * 2048 + n] = f2b(o1);
      ob[(r0 + 2) * 2048 + n] = f2b(o2);
      ob[(r0 + 3) * 2048 + n] = f2b(o3);
    } else {
      float* of = (float*)out;
      of[(r0 + 0) * 2048 + n] = o0;
      of[(r0 + 1) * 2048 + n] = o1;
      of[(r0 + 2) * 2048 + n] = o2;
      of[(r0 + 3) * 2048 + n] = o3;
    }
  }
}

extern "C" void kernel_launch(void* const* d_in, const int* in_sizes, int n_in,
                              void* d_out, int out_size, void* d_ws, size_t ws_size,
                              hipStream_t stream) {
  // inputs (dtype auto-detected): x (4,128,2048), a (4,1,128), W (4,1,64,128), S (1,2048,2048)
  const void* x = d_in[0];
  const void* a = d_in[1];
  const void* W = d_in[2];
  const void* S = d_in[3];

  char* ws = (char*)d_ws;
  u16* Wx      = (u16*)ws;                               // 16*2048*64*2 = 4 MiB
  float* s1t   = (float*)(ws + 4u * 1024 * 1024);        // 128 KiB
  float* s2t   = s1t + 2048 * 16;                        // 128 KiB
  float4* stat3= (float4*)(s2t + 2048 * 16);             // 512 KiB
  u32* cnt_p   = (u32*)((char*)stat3 + 512u * 1024);     // 2048*16*4 = 128 KiB (1 counter / 64B line)
  u32* col_m   = cnt_p + 2048 * 16;                      // 2 MiB
  float* col_v = (float*)(col_m + 2048 * CAP);           // 2 MiB
  u32* flag    = (u32*)(col_v + 2048 * CAP);             // 4 B
  // total ~8.9 MiB

  k_detect<<<1, 256, 0, stream>>>((const u32*)x, flag, (uint4*)cnt_p);
  k_wx<<<dim3(32, 16), 256, 0, stream>>>(x, W, a, Wx, s1t, s2t, flag);
  k_csc<<<2048, 256, 0, stream>>>(S, cnt_p, col_m, col_v, s1t, s2t, stat3, flag);
  k_out<<<8192, 256, 0, stream>>>(Wx, cnt_p, col_m, col_v, s1t, stat3, d_out, flag);
}

// Round 6
// 139.314 us; speedup vs baseline: 1.1910x; 1.1161x over previous
//
#include <hip/hip_runtime.h>
#include <hip/hip_bf16.h>

typedef unsigned short u16;
typedef unsigned int u32;

#define NEG_SLOPE 0.2f
#define ZTOLF 1e-9f
#define CAP 256          // max tracked nonzeros per column/row of S (mean ~102, sigma ~10)

typedef __attribute__((ext_vector_type(4))) float f32x4;
typedef __attribute__((ext_vector_type(8))) short bf16x8;

__device__ __forceinline__ float b2f(u16 v) {
  return __uint_as_float(((u32)v) << 16);
}
__device__ __forceinline__ u16 f2b(float f) {
  u32 u = __float_as_uint(f);
  return (u16)((u + 0x7fffu + ((u >> 16) & 1u)) >> 16);  // RNE
}
// dtype-flex input load: isbf=1 -> bf16 buffer, isbf=0 -> fp32 buffer
__device__ __forceinline__ float ldin(const void* p, size_t i, int isbf) {
  return isbf ? b2f(((const u16*)p)[i]) : ((const float*)p)[i];
}

// ---------------- K0: detect input dtype + zero the (padded) counters ----------------
__global__ __launch_bounds__(256) void k_detect(const u32* __restrict__ xw,
                                                u32* __restrict__ flag,
                                                uint4* __restrict__ cnt_p4) {  // 2048*16 u32 = 8192 uint4
  __shared__ u32 cnt_s[4];
  const int tid = threadIdx.x;
  const uint4 z = make_uint4(0u, 0u, 0u, 0u);
  for (int i = tid; i < 8192; i += 256) cnt_p4[i] = z;
  const u32 w = xw[tid];
  const u32 e = (w >> 7) & 0xffu;
  const int in = (e >= 118u && e <= 131u) ? 1 : 0;
  unsigned long long bal = __ballot(in);
  const int lane = tid & 63, wid = tid >> 6;
  if (lane == 0) cnt_s[wid] = (u32)__popcll(bal);
  __syncthreads();
  if (tid == 0) {
    u32 tot = cnt_s[0] + cnt_s[1] + cnt_s[2] + cnt_s[3];
    flag[0] = (tot >= 128u) ? 1u : 0u;
  }
}

// ---------------- K1: Wx[bp][n][f] (bf16) + fused s1t/s2t epilogue ----------------
// bf16 path: MFMA 16x16x32. Block = 64f x 64n for one bp; 4 waves, one 16-f strip each.
// fp32 path: original VALU tile GEMM (kept verbatim).
__global__ __launch_bounds__(256) void k_wx(const void* __restrict__ x,
                                            const void* __restrict__ W,
                                            const void* __restrict__ a,
                                            u16* __restrict__ Wx,
                                            float* __restrict__ s1t,
                                            float* __restrict__ s2t,
                                            const u32* __restrict__ flag) {
  __shared__ float smem_f[64 * 68 + 64 * 64];  // 33792 B; bf16 path reuses as XsT / red1/red2
  const int isbf = (int)flag[0];
  const int tid = threadIdx.x;
  const int n0 = blockIdx.x * 64;
  const int bp = blockIdx.y;
  const int b = bp >> 2, p = bp & 3;

  if (isbf) {
    // ---------- MFMA path ----------
    u16* XsT = (u16*)smem_f;                 // [n_local 64][g 128] padded to 136 (17408 B)
    const u16* xb = (const u16*)x + (size_t)b * 128 * 2048;
    const u16* Wb = (const u16*)W + (size_t)p * 64 * 128;
    // stage x tile transposed: XsT[n][g]
#pragma unroll
    for (int j = 0; j < 4; ++j) {
      const int idx = tid + j * 256;         // 0..1023
      const int g = idx >> 3, ng = (idx & 7) * 8;
      uint4 pk = *(const uint4*)(xb + (size_t)g * 2048 + n0 + ng);
      u16 e[8];
      e[0] = (u16)(pk.x & 0xffffu); e[1] = (u16)(pk.x >> 16);
      e[2] = (u16)(pk.y & 0xffffu); e[3] = (u16)(pk.y >> 16);
      e[4] = (u16)(pk.z & 0xffffu); e[5] = (u16)(pk.z >> 16);
      e[6] = (u16)(pk.w & 0xffffu); e[7] = (u16)(pk.w >> 16);
#pragma unroll
      for (int i = 0; i < 8; ++i) XsT[(ng + i) * 136 + g] = e[i];
    }
    __syncthreads();
    const int lane = tid & 63, wv = tid >> 6;
    const int f0 = wv * 16;
    const int arow = lane & 15, kgrp = lane >> 4;
    f32x4 zero = {0.f, 0.f, 0.f, 0.f};
    f32x4 acc[4] = {zero, zero, zero, zero};
#pragma unroll
    for (int kb = 0; kb < 4; ++kb) {
      // A: lane holds W[f0+arow][kb*32 + kgrp*8 + 0..7]
      bf16x8 afrag = *(const bf16x8*)(Wb + (size_t)(f0 + arow) * 128 + kb * 32 + kgrp * 8);
#pragma unroll
      for (int t = 0; t < 4; ++t) {
        // B: lane holds x[kb*32+kgrp*8+0..7][n0 + t*16 + arow]
        bf16x8 bfrag = *(const bf16x8*)&XsT[(t * 16 + arow) * 136 + kb * 32 + kgrp * 8];
        acc[t] = __builtin_amdgcn_mfma_f32_16x16x32_bf16(afrag, bfrag, acc[t], 0, 0, 0);
      }
    }
    // D layout: row f = f0 + 4*kgrp + v, col n_local = t*16 + arow
    float a1v[4], a2v[4];
#pragma unroll
    for (int v = 0; v < 4; ++v) {
      a1v[v] = b2f(((const u16*)a)[p * 128 + f0 + kgrp * 4 + v]);
      a2v[v] = b2f(((const u16*)a)[p * 128 + 64 + f0 + kgrp * 4 + v]);
    }
    __syncthreads();  // XsT reads complete in all waves; reuse as reduction space
    float* red1 = smem_f;             // [64][17]
    float* red2 = smem_f + 64 * 17;   // [64][17]
#pragma unroll
    for (int t = 0; t < 4; ++t) {
      const int n_l = t * 16 + arow;
      u32 lo = (u32)f2b(acc[t][0]) | ((u32)f2b(acc[t][1]) << 16);
      u32 hi = (u32)f2b(acc[t][2]) | ((u32)f2b(acc[t][3]) << 16);
      *(uint2*)(Wx + ((size_t)(bp * 2048 + n0 + n_l) * 64 + f0 + kgrp * 4)) = make_uint2(lo, hi);
      float p1 = a1v[0] * acc[t][0] + a1v[1] * acc[t][1] + a1v[2] * acc[t][2] + a1v[3] * acc[t][3];
      float p2 = a2v[0] * acc[t][0] + a2v[1] * acc[t][1] + a2v[2] * acc[t][2] + a2v[3] * acc[t][3];
      red1[n_l * 17 + wv * 4 + kgrp] = p1;
      red2[n_l * 17 + wv * 4 + kgrp] = p2;
    }
    __syncthreads();
    if (tid < 64) {
      float v1 = 0.f, v2 = 0.f;
#pragma unroll
      for (int k = 0; k < 16; ++k) {
        v1 += red1[tid * 17 + k];
        v2 += red2[tid * 17 + k];
      }
      s1t[(size_t)(n0 + tid) * 16 + bp] = v1;
      s2t[(size_t)(n0 + tid) * 16 + bp] = v2;
    }
    return;
  }

  // ---------- fp32 VALU fallback (original) ----------
  float* Wt = smem_f;            // [g][f] 64*68
  float* Xs = smem_f + 64 * 68;  // [g][n] 64*64
  const int tn = tid & 15, tf = tid >> 4;
  float acc[4][4] = {{0.f}};
  const size_t Wbase = (size_t)p * 64 * 128;
  const size_t xbase = (size_t)b * 128 * 2048;
  for (int kt = 0; kt < 2; ++kt) {
    const int g0 = kt * 64;
#pragma unroll
    for (int j = 0; j < 16; ++j) {
      int idx = tid + j * 256;
      int f = idx >> 6, g = idx & 63;
      Wt[g * 68 + f] = ((const float*)W)[Wbase + (size_t)f * 128 + g0 + g];
    }
#pragma unroll
    for (int j = 0; j < 16; ++j) {
      int idx = tid + j * 256;
      int g = idx >> 6, nn = idx & 63;
      Xs[g * 64 + nn] = ((const float*)x)[xbase + (size_t)(g0 + g) * 2048 + n0 + nn];
    }
    __syncthreads();
#pragma unroll 4
    for (int g = 0; g < 64; ++g) {
      float4 wv = *(const float4*)&Wt[g * 68 + tf * 4];
      float4 xv = *(const float4*)&Xs[g * 64 + tn * 4];
      acc[0][0] += wv.x * xv.x; acc[0][1] += wv.x * xv.y; acc[0][2] += wv.x * xv.z; acc[0][3] += wv.x * xv.w;
      acc[1][0] += wv.y * xv.x; acc[1][1] += wv.y * xv.y; acc[1][2] += wv.y * xv.z; acc[1][3] += wv.y * xv.w;
      acc[2][0] += wv.z * xv.x; acc[2][1] += wv.z * xv.y; acc[2][2] += wv.z * xv.z; acc[2][3] += wv.z * xv.w;
      acc[3][0] += wv.w * xv.x; acc[3][1] += wv.w * xv.y; acc[3][2] += wv.w * xv.z; acc[3][3] += wv.w * xv.w;
    }
    __syncthreads();
  }
#pragma unroll
  for (int j = 0; j < 4; ++j) {
    int n = n0 + tn * 4 + j;
    u32 lo = (u32)f2b(acc[0][j]) | ((u32)f2b(acc[1][j]) << 16);
    u32 hi = (u32)f2b(acc[2][j]) | ((u32)f2b(acc[3][j]) << 16);
    *(uint2*)(Wx + ((size_t)(bp * 2048 + n) * 64 + tf * 4)) = make_uint2(lo, hi);
  }
  float a1v[4], a2v[4];
#pragma unroll
  for (int fi = 0; fi < 4; ++fi) {
    a1v[fi] = ((const float*)a)[(size_t)p * 128 + tf * 4 + fi];
    a2v[fi] = ((const float*)a)[(size_t)p * 128 + 64 + tf * 4 + fi];
  }
  float* red1 = Wt;             // 64*17 floats
  float* red2 = Wt + 64 * 17;   // 64*17 floats
#pragma unroll
  for (int j = 0; j < 4; ++j) {
    float p1 = a1v[0] * acc[0][j] + a1v[1] * acc[1][j] + a1v[2] * acc[2][j] + a1v[3] * acc[3][j];
    float p2 = a2v[0] * acc[0][j] + a2v[1] * acc[1][j] + a2v[2] * acc[2][j] + a2v[3] * acc[3][j];
    red1[(tn * 4 + j) * 17 + tf] = p1;
    red2[(tn * 4 + j) * 17 + tf] = p2;
  }
  __syncthreads();
  if (tid < 64) {
    float v1 = 0.f, v2 = 0.f;
#pragma unroll
    for (int k = 0; k < 16; ++k) {
      v1 += red1[tid * 17 + k];
      v2 += red2[tid * 17 + k];
    }
    s1t[(size_t)(n0 + tid) * 16 + bp] = v1;
    s2t[(size_t)(n0 + tid) * 16 + bp] = v2;
  }
}

// ---------------- K2: block per row. Builds column lists (atomics) AND computes the
// per-row softmax stats inline (row list kept in LDS via prefix-scan).
// stat3[m][bp] = (s2, rowmax, invsum, 0) ----------------
__global__ __launch_bounds__(256) void k_csc(const void* __restrict__ S,
                                             u32* __restrict__ cnt_p,
                                             u32* __restrict__ col_m,
                                             float* __restrict__ col_v,
                                             const float* __restrict__ s1t,
                                             const float* __restrict__ s2t,
                                             float4* __restrict__ stat3,
                                             const u32* __restrict__ flag) {
  __shared__ u32 wsum[4];
  __shared__ u32 ls_n[CAP];      // compacted nonzero-row column indices of row m
  __shared__ u32 c2s;
  __shared__ float red[256];     // cross-thread reductions
  __shared__ float Mred[16];
  const int isbf = (int)flag[0];
  const int m = blockIdx.x;
  const int tid = threadIdx.x;
  const int lane = tid & 63, wid = tid >> 6;
  const int n0 = tid * 8;
  float v[8];
  if (isbf) {
    uint4 pk = ((const uint4*)S)[(size_t)m * 256 + tid];
    u32 wv[4] = {pk.x, pk.y, pk.z, pk.w};
#pragma unroll
    for (int j = 0; j < 4; ++j) {
      v[2 * j]     = b2f((u16)(wv[j] & 0xffffu));
      v[2 * j + 1] = b2f((u16)(wv[j] >> 16));
    }
  } else {
    float4 f0 = ((const float4*)S)[(size_t)m * 512 + 2 * tid];
    float4 f1 = ((const float4*)S)[(size_t)m * 512 + 2 * tid + 1];
    v[0] = f0.x; v[1] = f0.y; v[2] = f0.z; v[3] = f0.w;
    v[4] = f1.x; v[5] = f1.y; v[6] = f1.z; v[7] = f1.w;
  }
  // row-mask flags (|S+I| > tol)
  u32 rflags = 0, rc = 0;
#pragma unroll
  for (int j = 0; j < 8; ++j) {
    const int n = n0 + j;
    const float svd = (n == m) ? v[j] + 1.f : v[j];
    if (fabsf(svd) > ZTOLF) { rflags |= 1u << j; rc++; }
  }
  // block exclusive scan: wave shuffle scan + cross-wave via LDS
  u32 inc = rc;
#pragma unroll
  for (int off = 1; off < 64; off <<= 1) {
    u32 y = __shfl_up(inc, off);
    if (lane >= off) inc += y;
  }
  if (lane == 63) wsum[wid] = inc;
  __syncthreads();
  u32 wbase = 0;
#pragma unroll
  for (int k = 0; k < 4; ++k) wbase += (k < wid) ? wsum[k] : 0u;
  u32 pos = wbase + inc - rc;
#pragma unroll
  for (int j = 0; j < 8; ++j) {
    if ((rflags >> j) & 1u) {
      if (pos < CAP) ls_n[pos] = (u32)(n0 + j);
      pos++;
    }
  }
  if (tid == 255) c2s = min(wbase + inc, (u32)CAP);
  // column entries: padded-line atomics (2048 distinct lines, ~102 ops each)
#pragma unroll
  for (int j = 0; j < 8; ++j) {
    const float sv = v[j];
    if (sv != 0.f) {
      const int n = n0 + j;
      u32 slot = atomicAdd(&cnt_p[(size_t)n * 16], 1u);
      if (slot < CAP) {
        col_m[(size_t)n * CAP + slot] = (u32)m;
        col_v[(size_t)n * CAP + slot] = sv;
      }
    }
  }
  __syncthreads();
  // ---- fused per-row softmax stats ----
  const int c2 = (int)c2s;
  const int bp = tid & 15, sub = tid >> 4;
  const float s2v = s2t[(size_t)m * 16 + bp];
  float ev[16];
  float mymax = -3e38f;
#pragma unroll
  for (int k = 0; k < 16; ++k) {
    const int i = sub + k * 16;
    float e = -3e38f;
    if (i < c2) {
      const int nn = (int)ls_n[i];
      float s1 = s1t[(size_t)nn * 16 + bp];
      e = s1 + s2v;
      e = e >= 0.f ? e : NEG_SLOPE * e;   // leaky is monotone -> max commutes
    }
    ev[k] = e;
    mymax = fmaxf(mymax, e);
  }
  red[tid] = mymax;
  __syncthreads();
  if (tid < 16) {
    float M = -3e38f;
#pragma unroll
    for (int s = 0; s < 16; ++s) M = fmaxf(M, red[s * 16 + tid]);
    Mred[tid] = M;
  }
  __syncthreads();
  const float M = Mred[bp];
  float ssum = 0.f;
#pragma unroll
  for (int k = 0; k < 16; ++k) ssum += __expf(ev[k] - M);  // invalid -> exp(-inf) = 0
  __syncthreads();       // red[] reuse
  red[tid] = ssum;
  __syncthreads();
  if (tid < 16) {
    float Sm = 0.f;
#pragma unroll
    for (int s = 0; s < 16; ++s) Sm += red[s * 16 + tid];
    const float Mv = Mred[tid];
    const bool any = (Mv > -1e38f);
    const float rmx = any ? Mv : 0.f;
    const float inv = any ? 1.f / Sm : 0.f;
    const float s2o = s2t[(size_t)m * 16 + tid];
    stat3[(size_t)m * 16 + tid] = make_float4(s2o, rmx, inv, 0.f);
  }
}

// ---------------- K4: y[bp][f][n] = relu( sum_m Wx[bp][m][f] * S[m][n] * aij[bp][m][n] ) ----------------
// 256-thread blocks, bp split across blocks. grid = 2048 n x 4 bp-groups.
// XCD-pinned: xcd = bid&7 -> bpg = xcd>>1, so each XCD's Wx working set is 1 MiB (L2-resident).
__global__ __launch_bounds__(256, 8) void k_out(const u16* __restrict__ Wx,
                                                const u32* __restrict__ cnt_p,
                                                const u32* __restrict__ col_m,
                                                const float* __restrict__ col_v,
                                                const float* __restrict__ s1t,
                                                const float4* __restrict__ stat3,
                                                void* __restrict__ out,
                                                const u32* __restrict__ flag) {
  __shared__ u32 lds_m[CAP];
  __shared__ float lds_v[CAP];
  __shared__ float lds_w[CAP * 4];   // [i][bp4], 4 KB
  __shared__ float lds_r[3 * 256];   // quarter partials (3 KB)
  __shared__ float s1s4[4];
  const int isbf = (int)flag[0];
  const int tid = threadIdx.x;
  const int bid = blockIdx.x;
  const int xcd = bid & 7, lin = bid >> 3;
  const int bpg = xcd >> 1;                    // 4 bp per block; 2 XCDs per bpg
  const int n = ((xcd & 1) << 10) | lin;       // 2048 columns
  const int c = min((int)cnt_p[(size_t)n * 16], CAP);
  const int cpad = (c + 15) & ~15;             // 4 quarters x unroll-4
  if (tid < 4) s1s4[tid] = s1t[(size_t)n * 16 + bpg * 4 + tid];
  if (tid < cpad) {
    lds_m[tid] = (tid < c) ? col_m[(size_t)n * CAP + tid] : 0u;
    lds_v[tid] = (tid < c) ? col_v[(size_t)n * CAP + tid] : 0.f;
  }
  __syncthreads();
  // stage 2: weights for this block's 4 bp
  const int totk = cpad * 4;
  for (int k = tid; k < totk; k += 256) {
    const int i = k >> 2, bp4 = k & 3;
    const int bp = bpg * 4 + bp4;
    float w = 0.f;
    if (i < c) {
      const int mm = (int)lds_m[i];
      const float sv = lds_v[i];
      const float svd = (mm == n) ? sv + 1.f : sv;
      if (fabsf(svd) > ZTOLF) {
        float4 s = stat3[(size_t)mm * 16 + bp];   // (s2, rowmax, invsum)
        float e = s1s4[bp4] + s.x;
        e = e >= 0.f ? e : NEG_SLOPE * e;
        w = sv * __expf(e - s.y) * s.z;
      }
    }
    lds_w[k] = w;   // k = i*4 + bp4
  }
  __syncthreads();
  // stage 3: gather. wave h = entry-quarter; lane: bp4 = lane>>4, f4 = lane&15
  const int lane = tid & 63, h = tid >> 6;
  const int bp4 = lane >> 4, bp = bpg * 4 + bp4;
  const int f4 = lane & 15;
  const u16* wxp = Wx + (size_t)bp * (2048 * 64) + f4 * 4;
  float ac0 = 0.f, ac1 = 0.f, ac2 = 0.f, ac3 = 0.f;
  for (int base = h * 4; base < cpad; base += 16) {
    uint2 wd[4]; float ww[4];
#pragma unroll
    for (int j = 0; j < 4; ++j) {
      const int i = base + j;
      const int mm = (int)lds_m[i];
      wd[j] = *(const uint2*)(wxp + (size_t)mm * 64);
      ww[j] = lds_w[i * 4 + bp4];
    }
#pragma unroll
    for (int j = 0; j < 4; ++j) {
      const float w = ww[j];
      ac0 += w * b2f((u16)(wd[j].x & 0xffffu));
      ac1 += w * b2f((u16)(wd[j].x >> 16));
      ac2 += w * b2f((u16)(wd[j].y & 0xffffu));
      ac3 += w * b2f((u16)(wd[j].y >> 16));
    }
  }
  if (h > 0)
    *(float4*)&lds_r[(h - 1) * 256 + (bp4 * 16 + f4) * 4] = make_float4(ac0, ac1, ac2, ac3);
  __syncthreads();
  if (h == 0) {
#pragma unroll
    for (int q = 0; q < 3; ++q) {
      float4 r = *(const float4*)&lds_r[q * 256 + (bp4 * 16 + f4) * 4];
      ac0 += r.x; ac1 += r.y; ac2 += r.z; ac3 += r.w;
    }
    const float o0 = fmaxf(ac0, 0.f), o1 = fmaxf(ac1, 0.f);
    const float o2 = fmaxf(ac2, 0.f), o3 = fmaxf(ac3, 0.f);
    const size_t r0 = (size_t)(bp * 64 + f4 * 4);
    if (isbf) {
      u16* ob = (u16*)out;
      ob[(r0 + 0) * 2048 + n] = f2b(o0);
      ob[(r0 + 1) * 2048 + n] = f2b(o1);
      ob[(r0 + 2) * 2048 + n] = f2b(o2);
      ob[(r0 + 3) * 2048 + n] = f2b(o3);
    } else {
      float* of = (float*)out;
      of[(r0 + 0) * 2048 + n] = o0;
      of[(r0 + 1) * 2048 + n] = o1;
      of[(r0 + 2) * 2048 + n] = o2;
      of[(r0 + 3) * 2048 + n] = o3;
    }
  }
}

extern "C" void kernel_launch(void* const* d_in, const int* in_sizes, int n_in,
                              void* d_out, int out_size, void* d_ws, size_t ws_size,
                              hipStream_t stream) {
  // inputs (dtype auto-detected): x (4,128,2048), a (4,1,128), W (4,1,64,128), S (1,2048,2048)
  const void* x = d_in[0];
  const void* a = d_in[1];
  const void* W = d_in[2];
  const void* S = d_in[3];

  char* ws = (char*)d_ws;
  u16* Wx      = (u16*)ws;                               // 16*2048*64*2 = 4 MiB
  float* s1t   = (float*)(ws + 4u * 1024 * 1024);        // 128 KiB
  float* s2t   = s1t + 2048 * 16;                        // 128 KiB
  float4* stat3= (float4*)(s2t + 2048 * 16);             // 512 KiB
  u32* cnt_p   = (u32*)((char*)stat3 + 512u * 1024);     // 2048*16*4 = 128 KiB (1 counter / 64B line)
  u32* col_m   = cnt_p + 2048 * 16;                      // 2 MiB
  float* col_v = (float*)(col_m + 2048 * CAP);           // 2 MiB
  u32* flag    = (u32*)(col_v + 2048 * CAP);             // 4 B
  // total ~8.9 MiB

  k_detect<<<1, 256, 0, stream>>>((const u32*)x, flag, (uint4*)cnt_p);
  k_wx<<<dim3(32, 16), 256, 0, stream>>>(x, W, a, Wx, s1t, s2t, flag);
  k_csc<<<2048, 256, 0, stream>>>(S, cnt_p, col_m, col_v, s1t, s2t, stat3, flag);
  k_out<<<8192, 256, 0, stream>>>(Wx, cnt_p, col_m, col_v, s1t, stat3, d_out, flag);
}

// Round 8
// 129.568 us; speedup vs baseline: 1.2806x; 1.0752x over previous
//
#include <hip/hip_runtime.h>
#include <hip/hip_bf16.h>

typedef unsigned short u16;
typedef unsigned int u32;

#define NEG_SLOPE 0.2f
#define ZTOLF 1e-9f
#define CAP 256          // max tracked nonzeros per column/row of S (mean ~102, sigma ~10)

typedef __attribute__((ext_vector_type(4))) float f32x4;
typedef __attribute__((ext_vector_type(8))) short bf16x8;

__device__ __forceinline__ float b2f(u16 v) {
  return __uint_as_float(((u32)v) << 16);
}
__device__ __forceinline__ u16 f2b(float f) {
  u32 u = __float_as_uint(f);
  return (u16)((u + 0x7fffu + ((u >> 16) & 1u)) >> 16);  // RNE
}
// dtype-flex input load: isbf=1 -> bf16 buffer, isbf=0 -> fp32 buffer
__device__ __forceinline__ float ldin(const void* p, size_t i, int isbf) {
  return isbf ? b2f(((const u16*)p)[i]) : ((const float*)p)[i];
}

// ---------------- K0: detect input dtype + zero the (padded) counters ----------------
__global__ __launch_bounds__(256) void k_detect(const u32* __restrict__ xw,
                                                u32* __restrict__ flag,
                                                uint4* __restrict__ cnt_p4) {  // 2048*16 u32 = 8192 uint4
  __shared__ u32 cnt_s[4];
  const int tid = threadIdx.x;
  const uint4 z = make_uint4(0u, 0u, 0u, 0u);
  for (int i = tid; i < 8192; i += 256) cnt_p4[i] = z;
  const u32 w = xw[tid];
  const u32 e = (w >> 7) & 0xffu;
  const int in = (e >= 118u && e <= 131u) ? 1 : 0;
  unsigned long long bal = __ballot(in);
  const int lane = tid & 63, wid = tid >> 6;
  if (lane == 0) cnt_s[wid] = (u32)__popcll(bal);
  __syncthreads();
  if (tid == 0) {
    u32 tot = cnt_s[0] + cnt_s[1] + cnt_s[2] + cnt_s[3];
    flag[0] = (tot >= 128u) ? 1u : 0u;
  }
}

// ---------------- K1: Wx[bp][n][f] (bf16) + fused s1t/s2t epilogue ----------------
// bf16 path: MFMA 16x16x32. Block = 64f x 64n for one bp; 4 waves, one 16-f strip each.
// fp32 path: original VALU tile GEMM (kept verbatim).
__global__ __launch_bounds__(256) void k_wx(const void* __restrict__ x,
                                            const void* __restrict__ W,
                                            const void* __restrict__ a,
                                            u16* __restrict__ Wx,
                                            float* __restrict__ s1t,
                                            float* __restrict__ s2t,
                                            const u32* __restrict__ flag) {
  __shared__ float smem_f[64 * 68 + 64 * 64];  // 33792 B; bf16 path reuses as XsT / red1/red2
  const int isbf = (int)flag[0];
  const int tid = threadIdx.x;
  const int n0 = blockIdx.x * 64;
  const int bp = blockIdx.y;
  const int b = bp >> 2, p = bp & 3;

  if (isbf) {
    // ---------- MFMA path ----------
    u16* XsT = (u16*)smem_f;                 // [n_local 64][g 128] padded to 136 (17408 B)
    const u16* xb = (const u16*)x + (size_t)b * 128 * 2048;
    const u16* Wb = (const u16*)W + (size_t)p * 64 * 128;
    // stage x tile transposed: XsT[n][g]
#pragma unroll
    for (int j = 0; j < 4; ++j) {
      const int idx = tid + j * 256;         // 0..1023
      const int g = idx >> 3, ng = (idx & 7) * 8;
      uint4 pk = *(const uint4*)(xb + (size_t)g * 2048 + n0 + ng);
      u16 e[8];
      e[0] = (u16)(pk.x & 0xffffu); e[1] = (u16)(pk.x >> 16);
      e[2] = (u16)(pk.y & 0xffffu); e[3] = (u16)(pk.y >> 16);
      e[4] = (u16)(pk.z & 0xffffu); e[5] = (u16)(pk.z >> 16);
      e[6] = (u16)(pk.w & 0xffffu); e[7] = (u16)(pk.w >> 16);
#pragma unroll
      for (int i = 0; i < 8; ++i) XsT[(ng + i) * 136 + g] = e[i];
    }
    __syncthreads();
    const int lane = tid & 63, wv = tid >> 6;
    const int f0 = wv * 16;
    const int arow = lane & 15, kgrp = lane >> 4;
    f32x4 zero = {0.f, 0.f, 0.f, 0.f};
    f32x4 acc[4] = {zero, zero, zero, zero};
#pragma unroll
    for (int kb = 0; kb < 4; ++kb) {
      // A: lane holds W[f0+arow][kb*32 + kgrp*8 + 0..7]
      bf16x8 afrag = *(const bf16x8*)(Wb + (size_t)(f0 + arow) * 128 + kb * 32 + kgrp * 8);
#pragma unroll
      for (int t = 0; t < 4; ++t) {
        // B: lane holds x[kb*32+kgrp*8+0..7][n0 + t*16 + arow]
        bf16x8 bfrag = *(const bf16x8*)&XsT[(t * 16 + arow) * 136 + kb * 32 + kgrp * 8];
        acc[t] = __builtin_amdgcn_mfma_f32_16x16x32_bf16(afrag, bfrag, acc[t], 0, 0, 0);
      }
    }
    // D layout: row f = f0 + 4*kgrp + v, col n_local = t*16 + arow
    float a1v[4], a2v[4];
#pragma unroll
    for (int v = 0; v < 4; ++v) {
      a1v[v] = b2f(((const u16*)a)[p * 128 + f0 + kgrp * 4 + v]);
      a2v[v] = b2f(((const u16*)a)[p * 128 + 64 + f0 + kgrp * 4 + v]);
    }
    __syncthreads();  // XsT reads complete in all waves; reuse as reduction space
    float* red1 = smem_f;             // [64][17]
    float* red2 = smem_f + 64 * 17;   // [64][17]
#pragma unroll
    for (int t = 0; t < 4; ++t) {
      const int n_l = t * 16 + arow;
      u32 lo = (u32)f2b(acc[t][0]) | ((u32)f2b(acc[t][1]) << 16);
      u32 hi = (u32)f2b(acc[t][2]) | ((u32)f2b(acc[t][3]) << 16);
      *(uint2*)(Wx + ((size_t)(bp * 2048 + n0 + n_l) * 64 + f0 + kgrp * 4)) = make_uint2(lo, hi);
      float p1 = a1v[0] * acc[t][0] + a1v[1] * acc[t][1] + a1v[2] * acc[t][2] + a1v[3] * acc[t][3];
      float p2 = a2v[0] * acc[t][0] + a2v[1] * acc[t][1] + a2v[2] * acc[t][2] + a2v[3] * acc[t][3];
      red1[n_l * 17 + wv * 4 + kgrp] = p1;
      red2[n_l * 17 + wv * 4 + kgrp] = p2;
    }
    __syncthreads();
    if (tid < 64) {
      float v1 = 0.f, v2 = 0.f;
#pragma unroll
      for (int k = 0; k < 16; ++k) {
        v1 += red1[tid * 17 + k];
        v2 += red2[tid * 17 + k];
      }
      s1t[(size_t)(n0 + tid) * 16 + bp] = v1;
      s2t[(size_t)(n0 + tid) * 16 + bp] = v2;
    }
    return;
  }

  // ---------- fp32 VALU fallback (original) ----------
  float* Wt = smem_f;            // [g][f] 64*68
  float* Xs = smem_f + 64 * 68;  // [g][n] 64*64
  const int tn = tid & 15, tf = tid >> 4;
  float acc[4][4] = {{0.f}};
  const size_t Wbase = (size_t)p * 64 * 128;
  const size_t xbase = (size_t)b * 128 * 2048;
  for (int kt = 0; kt < 2; ++kt) {
    const int g0 = kt * 64;
#pragma unroll
    for (int j = 0; j < 16; ++j) {
      int idx = tid + j * 256;
      int f = idx >> 6, g = idx & 63;
      Wt[g * 68 + f] = ((const float*)W)[Wbase + (size_t)f * 128 + g0 + g];
    }
#pragma unroll
    for (int j = 0; j < 16; ++j) {
      int idx = tid + j * 256;
      int g = idx >> 6, nn = idx & 63;
      Xs[g * 64 + nn] = ((const float*)x)[xbase + (size_t)(g0 + g) * 2048 + n0 + nn];
    }
    __syncthreads();
#pragma unroll 4
    for (int g = 0; g < 64; ++g) {
      float4 wv = *(const float4*)&Wt[g * 68 + tf * 4];
      float4 xv = *(const float4*)&Xs[g * 64 + tn * 4];
      acc[0][0] += wv.x * xv.x; acc[0][1] += wv.x * xv.y; acc[0][2] += wv.x * xv.z; acc[0][3] += wv.x * xv.w;
      acc[1][0] += wv.y * xv.x; acc[1][1] += wv.y * xv.y; acc[1][2] += wv.y * xv.z; acc[1][3] += wv.y * xv.w;
      acc[2][0] += wv.z * xv.x; acc[2][1] += wv.z * xv.y; acc[2][2] += wv.z * xv.z; acc[2][3] += wv.z * xv.w;
      acc[3][0] += wv.w * xv.x; acc[3][1] += wv.w * xv.y; acc[3][2] += wv.w * xv.z; acc[3][3] += wv.w * xv.w;
    }
    __syncthreads();
  }
#pragma unroll
  for (int j = 0; j < 4; ++j) {
    int n = n0 + tn * 4 + j;
    u32 lo = (u32)f2b(acc[0][j]) | ((u32)f2b(acc[1][j]) << 16);
    u32 hi = (u32)f2b(acc[2][j]) | ((u32)f2b(acc[3][j]) << 16);
    *(uint2*)(Wx + ((size_t)(bp * 2048 + n) * 64 + tf * 4)) = make_uint2(lo, hi);
  }
  float a1v[4], a2v[4];
#pragma unroll
  for (int fi = 0; fi < 4; ++fi) {
    a1v[fi] = ((const float*)a)[(size_t)p * 128 + tf * 4 + fi];
    a2v[fi] = ((const float*)a)[(size_t)p * 128 + 64 + tf * 4 + fi];
  }
  float* red1 = Wt;             // 64*17 floats
  float* red2 = Wt + 64 * 17;   // 64*17 floats
#pragma unroll
  for (int j = 0; j < 4; ++j) {
    float p1 = a1v[0] * acc[0][j] + a1v[1] * acc[1][j] + a1v[2] * acc[2][j] + a1v[3] * acc[3][j];
    float p2 = a2v[0] * acc[0][j] + a2v[1] * acc[1][j] + a2v[2] * acc[2][j] + a2v[3] * acc[3][j];
    red1[(tn * 4 + j) * 17 + tf] = p1;
    red2[(tn * 4 + j) * 17 + tf] = p2;
  }
  __syncthreads();
  if (tid < 64) {
    float v1 = 0.f, v2 = 0.f;
#pragma unroll
    for (int k = 0; k < 16; ++k) {
      v1 += red1[tid * 17 + k];
      v2 += red2[tid * 17 + k];
    }
    s1t[(size_t)(n0 + tid) * 16 + bp] = v1;
    s2t[(size_t)(n0 + tid) * 16 + bp] = v2;
  }
}

// ---------------- K2: block per row. Builds column lists (atomics) AND computes the
// per-row softmax stats inline (row list kept in LDS via prefix-scan).
// stat3[m][bp] = (s2, rowmax, invsum, 0) ----------------
__global__ __launch_bounds__(256) void k_csc(const void* __restrict__ S,
                                             u32* __restrict__ cnt_p,
                                             u32* __restrict__ col_m,
                                             float* __restrict__ col_v,
                                             const float* __restrict__ s1t,
                                             const float* __restrict__ s2t,
                                             float4* __restrict__ stat3,
                                             const u32* __restrict__ flag) {
  __shared__ u32 wsum[4];
  __shared__ u32 ls_n[CAP];      // compacted nonzero-row column indices of row m
  __shared__ u32 c2s;
  __shared__ float red[256];     // cross-thread reductions
  __shared__ float Mred[16];
  const int isbf = (int)flag[0];
  const int m = blockIdx.x;
  const int tid = threadIdx.x;
  const int lane = tid & 63, wid = tid >> 6;
  const int n0 = tid * 8;
  float v[8];
  if (isbf) {
    uint4 pk = ((const uint4*)S)[(size_t)m * 256 + tid];
    u32 wv[4] = {pk.x, pk.y, pk.z, pk.w};
#pragma unroll
    for (int j = 0; j < 4; ++j) {
      v[2 * j]     = b2f((u16)(wv[j] & 0xffffu));
      v[2 * j + 1] = b2f((u16)(wv[j] >> 16));
    }
  } else {
    float4 f0 = ((const float4*)S)[(size_t)m * 512 + 2 * tid];
    float4 f1 = ((const float4*)S)[(size_t)m * 512 + 2 * tid + 1];
    v[0] = f0.x; v[1] = f0.y; v[2] = f0.z; v[3] = f0.w;
    v[4] = f1.x; v[5] = f1.y; v[6] = f1.z; v[7] = f1.w;
  }
  // row-mask flags (|S+I| > tol)
  u32 rflags = 0, rc = 0;
#pragma unroll
  for (int j = 0; j < 8; ++j) {
    const int n = n0 + j;
    const float svd = (n == m) ? v[j] + 1.f : v[j];
    if (fabsf(svd) > ZTOLF) { rflags |= 1u << j; rc++; }
  }
  // block exclusive scan: wave shuffle scan + cross-wave via LDS
  u32 inc = rc;
#pragma unroll
  for (int off = 1; off < 64; off <<= 1) {
    u32 y = __shfl_up(inc, off);
    if (lane >= off) inc += y;
  }
  if (lane == 63) wsum[wid] = inc;
  __syncthreads();
  u32 wbase = 0;
#pragma unroll
  for (int k = 0; k < 4; ++k) wbase += (k < wid) ? wsum[k] : 0u;
  u32 pos = wbase + inc - rc;
#pragma unroll
  for (int j = 0; j < 8; ++j) {
    if ((rflags >> j) & 1u) {
      if (pos < CAP) ls_n[pos] = (u32)(n0 + j);
      pos++;
    }
  }
  if (tid == 255) c2s = min(wbase + inc, (u32)CAP);
  // column entries: padded-line atomics (2048 distinct lines, ~102 ops each)
#pragma unroll
  for (int j = 0; j < 8; ++j) {
    const float sv = v[j];
    if (sv != 0.f) {
      const int n = n0 + j;
      u32 slot = atomicAdd(&cnt_p[(size_t)n * 16], 1u);
      if (slot < CAP) {
        col_m[(size_t)n * CAP + slot] = (u32)m;
        col_v[(size_t)n * CAP + slot] = sv;
      }
    }
  }
  __syncthreads();
  // ---- fused per-row softmax stats ----
  const int c2 = (int)c2s;
  const int bp = tid & 15, sub = tid >> 4;
  const float s2v = s2t[(size_t)m * 16 + bp];
  float ev[16];
  float mymax = -3e38f;
#pragma unroll
  for (int k = 0; k < 16; ++k) {
    const int i = sub + k * 16;
    float e = -3e38f;
    if (i < c2) {
      const int nn = (int)ls_n[i];
      float s1 = s1t[(size_t)nn * 16 + bp];
      e = s1 + s2v;
      e = e >= 0.f ? e : NEG_SLOPE * e;   // leaky is monotone -> max commutes
    }
    ev[k] = e;
    mymax = fmaxf(mymax, e);
  }
  red[tid] = mymax;
  __syncthreads();
  if (tid < 16) {
    float M = -3e38f;
#pragma unroll
    for (int s = 0; s < 16; ++s) M = fmaxf(M, red[s * 16 + tid]);
    Mred[tid] = M;
  }
  __syncthreads();
  const float M = Mred[bp];
  float ssum = 0.f;
#pragma unroll
  for (int k = 0; k < 16; ++k) ssum += __expf(ev[k] - M);  // invalid -> exp(-inf) = 0
  __syncthreads();       // red[] reuse
  red[tid] = ssum;
  __syncthreads();
  if (tid < 16) {
    float Sm = 0.f;
#pragma unroll
    for (int s = 0; s < 16; ++s) Sm += red[s * 16 + tid];
    const float Mv = Mred[tid];
    const bool any = (Mv > -1e38f);
    const float rmx = any ? Mv : 0.f;
    const float inv = any ? 1.f / Sm : 0.f;
    const float s2o = s2t[(size_t)m * 16 + tid];
    stat3[(size_t)m * 16 + tid] = make_float4(s2o, rmx, inv, 0.f);
  }
}

// ---------------- K4: y[bp][f][n] = relu( sum_m Wx[bp][m][f] * S[m][n] * aij[bp][m][n] ) ----------------
// v3: dwordx4 gathers (16 B/lane), 2-deep software pipeline, padded entry lists.
// lane = (e2 = entry parity, bp4, f8). 256-thread blocks; grid = 2048 n x 4 bp-groups; XCD-pinned.
__global__ __launch_bounds__(256, 8) void k_out(const u16* __restrict__ Wx,
                                                const u32* __restrict__ cnt_p,
                                                const u32* __restrict__ col_m,
                                                const float* __restrict__ col_v,
                                                const float* __restrict__ s1t,
                                                const float4* __restrict__ stat3,
                                                void* __restrict__ out,
                                                const u32* __restrict__ flag) {
  __shared__ u32 lds_m[CAP + 8];
  __shared__ float lds_v[CAP + 8];
  __shared__ float lds_w[(CAP + 8) * 4];  // [i][bp4]
  __shared__ float lds_r[3 * 256];        // wave partials
  __shared__ float s1s4[4];
  const int isbf = (int)flag[0];
  const int tid = threadIdx.x;
  const int bid = blockIdx.x;
  const int xcd = bid & 7, lin = bid >> 3;
  const int bpg = xcd >> 1;                    // 4 bp per block; 2 XCDs per bpg
  const int n = ((xcd & 1) << 10) | lin;       // 2048 columns
  const int c = min((int)cnt_p[(size_t)n * 16], CAP);
  const int cpad = (c + 15) & ~15;             // multiple of 16 (pipeline step)
  if (tid < 4) s1s4[tid] = s1t[(size_t)n * 16 + bpg * 4 + tid];
  for (int t2 = tid; t2 < cpad + 8; t2 += 256) {
    lds_m[t2] = (t2 < c) ? col_m[(size_t)n * CAP + t2] : 0u;
    lds_v[t2] = (t2 < c) ? col_v[(size_t)n * CAP + t2] : 0.f;
  }
  __syncthreads();
  // stage 2: weights for this block's 4 bp (pad entries -> w = 0)
  const int totk = (cpad + 8) * 4;
  for (int k = tid; k < totk; k += 256) {
    const int i = k >> 2, bp4 = k & 3;
    const int bp = bpg * 4 + bp4;
    float w = 0.f;
    if (i < c) {
      const int mm = (int)lds_m[i];
      const float sv = lds_v[i];
      const float svd = (mm == n) ? sv + 1.f : sv;
      if (fabsf(svd) > ZTOLF) {
        float4 s = stat3[(size_t)mm * 16 + bp];   // (s2, rowmax, invsum)
        float e = s1s4[bp4] + s.x;
        e = e >= 0.f ? e : NEG_SLOPE * e;
        w = sv * __expf(e - s.y) * s.z;
      }
    }
    lds_w[k] = w;   // k = i*4 + bp4
  }
  __syncthreads();
  // stage 3: gather. lane: e2 = lane>>5, bp4 = (lane>>3)&3, f8 = lane&7.
  // wave h handles entries {h*2 + e2 + 8*t}; dwordx4 = 8 f values per lane.
  const int lane = tid & 63, h = tid >> 6;
  const int e2 = lane >> 5;
  const int bp4 = (lane >> 3) & 3;
  const int bp = bpg * 4 + bp4;
  const int f8 = lane & 7;
  const u16* wxp = Wx + (size_t)bp * (2048 * 64) + f8 * 8;
  float acc[8] = {0.f, 0.f, 0.f, 0.f, 0.f, 0.f, 0.f, 0.f};
  int i = h * 2 + e2;
  u32 mmA = lds_m[i];
  float wA = lds_w[i * 4 + bp4];
  uint4 dA = *(const uint4*)(wxp + (size_t)mmA * 64);
  for (int base = 0; base < cpad; base += 16) {
    const int iB = i + 8;
    const u32 mmB = lds_m[iB];
    const float wB = lds_w[iB * 4 + bp4];
    const uint4 dB = *(const uint4*)(wxp + (size_t)mmB * 64);
    acc[0] += wA * b2f((u16)(dA.x & 0xffffu)); acc[1] += wA * b2f((u16)(dA.x >> 16));
    acc[2] += wA * b2f((u16)(dA.y & 0xffffu)); acc[3] += wA * b2f((u16)(dA.y >> 16));
    acc[4] += wA * b2f((u16)(dA.z & 0xffffu)); acc[5] += wA * b2f((u16)(dA.z >> 16));
    acc[6] += wA * b2f((u16)(dA.w & 0xffffu)); acc[7] += wA * b2f((u16)(dA.w >> 16));
    i = iB + 8;
    mmA = lds_m[i];
    wA = lds_w[i * 4 + bp4];
    dA = *(const uint4*)(wxp + (size_t)mmA * 64);
    acc[0] += wB * b2f((u16)(dB.x & 0xffffu)); acc[1] += wB * b2f((u16)(dB.x >> 16));
    acc[2] += wB * b2f((u16)(dB.y & 0xffffu)); acc[3] += wB * b2f((u16)(dB.y >> 16));
    acc[4] += wB * b2f((u16)(dB.z & 0xffffu)); acc[5] += wB * b2f((u16)(dB.z >> 16));
    acc[6] += wB * b2f((u16)(dB.w & 0xffffu)); acc[7] += wB * b2f((u16)(dB.w >> 16));
  }
  // fold the two entry-parities: lanes l and l^32 hold the same (bp4, f8)
#pragma unroll
  for (int k = 0; k < 8; ++k) acc[k] += __shfl_xor(acc[k], 32);
  if (h > 0 && e2 == 0) {
    float* dst = &lds_r[(h - 1) * 256 + bp4 * 64 + f8 * 8];
    *(float4*)dst = make_float4(acc[0], acc[1], acc[2], acc[3]);
    *(float4*)(dst + 4) = make_float4(acc[4], acc[5], acc[6], acc[7]);
  }
  __syncthreads();
  if (h == 0 && e2 == 0) {
#pragma unroll
    for (int q = 0; q < 3; ++q) {
      const float* src = &lds_r[q * 256 + bp4 * 64 + f8 * 8];
#pragma unroll
      for (int k = 0; k < 8; ++k) acc[k] += src[k];
    }
    const size_t r0 = (size_t)(bp * 64 + f8 * 8);
    if (isbf) {
      u16* ob = (u16*)out;
#pragma unroll
      for (int k = 0; k < 8; ++k) ob[(r0 + k) * 2048 + n] = f2b(fmaxf(acc[k], 0.f));
    } else {
      float* of = (float*)out;
#pragma unroll
      for (int k = 0; k < 8; ++k) of[(r0 + k) * 2048 + n] = fmaxf(acc[k], 0.f);
    }
  }
}

extern "C" void kernel_launch(void* const* d_in, const int* in_sizes, int n_in,
                              void* d_out, int out_size, void* d_ws, size_t ws_size,
                              hipStream_t stream) {
  // inputs (dtype auto-detected): x (4,128,2048), a (4,1,128), W (4,1,64,128), S (1,2048,2048)
  const void* x = d_in[0];
  const void* a = d_in[1];
  const void* W = d_in[2];
  const void* S = d_in[3];

  char* ws = (char*)d_ws;
  u16* Wx      = (u16*)ws;                               // 16*2048*64*2 = 4 MiB
  float* s1t   = (float*)(ws + 4u * 1024 * 1024);        // 128 KiB
  float* s2t   = s1t + 2048 * 16;                        // 128 KiB
  float4* stat3= (float4*)(s2t + 2048 * 16);             // 512 KiB
  u32* cnt_p   = (u32*)((char*)stat3 + 512u * 1024);     // 2048*16*4 = 128 KiB (1 counter / 64B line)
  u32* col_m   = cnt_p + 2048 * 16;                      // 2 MiB
  float* col_v = (float*)(col_m + 2048 * CAP);           // 2 MiB
  u32* flag    = (u32*)(col_v + 2048 * CAP);             // 4 B
  // total ~8.9 MiB

  k_detect<<<1, 256, 0, stream>>>((const u32*)x, flag, (uint4*)cnt_p);
  k_wx<<<dim3(32, 16), 256, 0, stream>>>(x, W, a, Wx, s1t, s2t, flag);
  k_csc<<<2048, 256, 0, stream>>>(S, cnt_p, col_m, col_v, s1t, s2t, stat3, flag);
  k_out<<<8192, 256, 0, stream>>>(Wx, cnt_p, col_m, col_v, s1t, stat3, d_out, flag);
}